// Round 17
// baseline (121.822 us; speedup 1.0000x reference)
//
#include <hip/hip_runtime.h>
#include <cstdint>
#include <cstddef>

// ---- types ----------------------------------------------------------------
typedef __bf16 bf8 __attribute__((ext_vector_type(8)));
typedef float f32x4 __attribute__((ext_vector_type(4)));
typedef float f32x2 __attribute__((ext_vector_type(2)));
typedef float f32x4u __attribute__((ext_vector_type(4), aligned(4)));
typedef unsigned short us8 __attribute__((ext_vector_type(8)));
typedef unsigned short us4 __attribute__((ext_vector_type(4)));
typedef unsigned int u32x4 __attribute__((ext_vector_type(4)));
typedef unsigned int u32x2 __attribute__((ext_vector_type(2)));

__device__ __forceinline__ uint16_t f2b(float f) {
    uint32_t u = __builtin_bit_cast(uint32_t, f);
    u += 0x7FFFu + ((u >> 16) & 1u);          // RNE
    return (uint16_t)(u >> 16);
}
__device__ __forceinline__ float b2f(uint16_t h) {
    uint32_t u = ((uint32_t)h) << 16;
    return __builtin_bit_cast(float, u);
}
#if __has_builtin(__builtin_amdgcn_cvt_pk_bf16_f32)
__device__ __forceinline__ uint32_t pkbf(float a, float b) {
    auto r = __builtin_amdgcn_cvt_pk_bf16_f32(a, b);
    return __builtin_bit_cast(uint32_t, r);
}
#else
__device__ __forceinline__ uint32_t pkbf(float a, float b) {
    return (uint32_t)f2b(a) | ((uint32_t)f2b(b) << 16);
}
#endif
__device__ __forceinline__ f32x2 up01(uint32_t d) {
    f32x2 r;
    r[0] = __builtin_bit_cast(float, d << 16);
    r[1] = __builtin_bit_cast(float, d & 0xffff0000u);
    return r;
}
__device__ __forceinline__ float gelu_fast(float y) {
    float y3 = y * y * y;
    float z2 = 1.5957691216f * (y + 0.044715f * y3);
    float u = __expf(-z2);
    return y * __builtin_amdgcn_rcpf(1.0f + u);
}

#define MFMA(a, b, c) __builtin_amdgcn_mfma_f32_16x16x32_bf16( \
    __builtin_bit_cast(bf8, (a)), __builtin_bit_cast(bf8, (b)), (c), 0, 0, 0)

// ---- prep: cast+transpose weights into ws ---------------------------------
// ws layout (uint16_t): w1t[64][32] @0, w2t[64][64] @2048, w3t[3072][64] @6144
// w3t rows permuted k = i*3+f -> k' = f*32+i (matches phase B's per-f
// sequential production; phase D mechanics unchanged).
__global__ void prep_weights(const float* __restrict__ W1,
                             const float* __restrict__ W2,
                             const float* __restrict__ W3,
                             uint16_t* __restrict__ wt) {
    __shared__ float tile[32][33];
    int bx = blockIdx.x;
    if (bx < 192) {
        int kb = (bx & 1) * 32;
        int jb = (bx >> 1) * 32;
        int tx = threadIdx.x & 31, ty = threadIdx.x >> 5;   // 32 x 8
        #pragma unroll
        for (int l = 0; l < 4; ++l)
            tile[ty + 8 * l][tx] = W3[(size_t)(kb + ty + 8 * l) * 3072 + jb + tx];
        __syncthreads();
        #pragma unroll
        for (int l = 0; l < 4; ++l) {
            unsigned j = jb + ty + 8 * l;          // source col = o*96 + i*3 + f
            unsigned o = j / 96u, rem = j - o * 96u;
            unsigned i = rem / 3u, f = rem - i * 3u;
            unsigned jp = o * 96u + f * 32u + i;   // dest row, k' = f*32+i
            wt[6144 + (size_t)jp * 64 + kb + tx] = f2b(tile[tx][ty + 8 * l]);
        }
    } else {
        int t = (bx - 192) * 256 + threadIdx.x;   // 0..6143
        if (t < 2048) {                            // W1: [32][64]
            int i = t >> 6, j = t & 63;
            wt[j * 32 + i] = f2b(W1[t]);
        } else {                                   // W2: [64][64]
            int t2 = t - 2048;
            int k = t2 >> 6, j = t2 & 63;
            wt[2048 + j * 64 + k] = f2b(W2[t2]);
        }
    }
}

// ---- fused main kernel ----------------------------------------------------
// R17 = R16 (verified best, bench 121.1) + XOR bank-swizzle on sh_t01/sh_t2.
// R16 residual: SQ_LDS_BANK_CONFLICT ~901K — stride 100 dwords = 4 mod 32
// makes phase-D t01 reads an 8-way conflict (bank = 4*((n+q+4mt)&7));
// t2 similar. Swizzle: t01 col ^= (e&7)<<2 (dword units, bits 2-4, u32x4
// alignment & range <100 preserved); t2 col ^= (e&3)<<3 (elem units, bits
// 3-4, us8/us4 alignment & range <104 preserved). Store (B) and read (D)
// use the same involution keyed on the same e; XOR bits don't overlap the
// within-vector bits, so element k' <-> col k'^swz exactly — pure layout
// permutation, bit-identical output. Expected ~2-4-way instead of 8-way.
__global__ __launch_bounds__(512, 4) void pairconv_main(
    const float* __restrict__ edges, const float* __restrict__ feats,
    const float* __restrict__ basis,
    const float* __restrict__ b1, const float* __restrict__ g1, const float* __restrict__ be1,
    const float* __restrict__ b2, const float* __restrict__ g2, const float* __restrict__ be2,
    const uint16_t* __restrict__ wt, float* __restrict__ out) {

    __shared__ __align__(16) uint32_t sh_t01[64 * 100];   // 25.0 KiB (m0,m1 packed)
    __shared__ __align__(16) uint16_t sh_t2[64 * 104];    // 13.0 KiB (m2)
    __shared__ __align__(16) uint16_t sh_h[4][16 * 64];   // 8 KiB (h1 then h2)
    __shared__ __align__(16) float sh_out[64][100];       // 25.0 KiB (96 used + pad)

    const int tid = threadIdx.x;
    const int e0 = blockIdx.x * 64;
    const int lane = tid & 63, w = tid >> 6;              // w in 0..7
    const int n = lane & 15, q = lane >> 4;

    if (w >= 4) {
        // ---------------- Phase B (waves 4-7; per-f sequential, low-reg) ----
        const int e = (tid - 256) >> 2, iq = tid & 3;   // 64 edges x 4 quarters
        const int swz1 = (e & 7) << 2;                  // t01 swizzle (dwords)
        const int swz2 = (e & 3) << 3;                  // t2 swizzle (elems)
        f32x4 fv[6];
        const float* fp = feats + (size_t)(e0 + e) * 96 + iq * 24;
        #pragma unroll
        for (int l = 0; l < 6; ++l) fv[l] = *(const f32x4u*)(fp + l * 4);
        const float* bpp = basis + (size_t)(e0 + e) * 27;
        const float* fvs = (const float*)fv;   // 24 floats = 8 i x 3

        #pragma unroll 1
        for (int f = 0; f < 3; ++f) {
            float bpf[9];
            #pragma unroll
            for (int m3 = 0; m3 < 3; ++m3) {   // m_in
                bpf[m3 * 3 + 0] = bpp[m3 * 9 + f * 3 + 0];
                bpf[m3 * 3 + 1] = bpp[m3 * 9 + f * 3 + 1];
                bpf[m3 * 3 + 2] = bpp[m3 * 9 + f * 3 + 2];
            }
            uint32_t t01f[8]; uint16_t t2f[8];
            #pragma unroll
            for (int ii = 0; ii < 8; ++ii) {
                float a0 = fvs[ii * 3], a1 = fvs[ii * 3 + 1], a2 = fvs[ii * 3 + 2];
                float v0 = a0 * bpf[0] + a1 * bpf[3] + a2 * bpf[6];
                float v1 = a0 * bpf[1] + a1 * bpf[4] + a2 * bpf[7];
                float v2 = a0 * bpf[2] + a1 * bpf[5] + a2 * bpf[8];
                t01f[ii] = pkbf(v0, v1);
                t2f[ii]  = (uint16_t)pkbf(v2, v2);
            }
            const int c0 = f * 32 + iq * 8;        // k' = f*32 + i
            *(u32x4*)&sh_t01[e * 100 + (c0 ^ swz1)]       = *(u32x4*)&t01f[0];
            *(u32x4*)&sh_t01[e * 100 + ((c0 + 4) ^ swz1)] = *(u32x4*)&t01f[4];
            *(us8*)&sh_t2[e * 104 + (c0 ^ swz2)]          = *(us8*)&t2f[0];
        }
    } else {
        // ---------------- Phase C (waves 0-3; LN via acc-recompute) ---------
        const int eb = e0 + w * 16;
        f32x4 ex0 = *(const f32x4*)(edges + (size_t)(eb + n) * 32 + q * 8);
        f32x4 ex1 = *(const f32x4*)(edges + (size_t)(eb + n) * 32 + q * 8 + 4);

        us8 bx;
        {
            u32x4 bxp;
            bxp[0] = pkbf(ex0[0], ex0[1]); bxp[1] = pkbf(ex0[2], ex0[3]);
            bxp[2] = pkbf(ex1[0], ex1[1]); bxp[3] = pkbf(ex1[2], ex1[3]);
            bx = __builtin_bit_cast(us8, bxp);
        }
        {
            f32x4 acc[4];
            #pragma unroll
            for (int mt = 0; mt < 4; ++mt) {
                us8 a = *(const us8*)(wt + (mt * 16 + n) * 32 + q * 8);
                f32x4 z = {0.f, 0.f, 0.f, 0.f};
                acc[mt] = MFMA(a, bx, z);
            }
            float s1 = 0.f, s2 = 0.f;
            #pragma unroll
            for (int mt = 0; mt < 4; ++mt) {
                f32x4 bb = *(const f32x4*)&b1[mt * 16 + q * 4];
                #pragma unroll
                for (int r = 0; r < 4; ++r) {
                    float x = acc[mt][r] + bb[r];
                    s1 += x; s2 += x * x;
                }
            }
            s1 += __shfl_xor(s1, 16, 64); s1 += __shfl_xor(s1, 32, 64);
            s2 += __shfl_xor(s2, 16, 64); s2 += __shfl_xor(s2, 32, 64);
            float mean = s1 * (1.f / 64.f);
            float var  = s2 * (1.f / 64.f) - mean * mean;
            float rs = __builtin_amdgcn_rsqf(var + 1e-5f);
            #pragma unroll
            for (int mt = 0; mt < 4; ++mt) {
                int bo = mt * 16 + q * 4;
                asm volatile("" : "+v"(bo));   // force bias reload (no CSE)
                f32x4 bb = *(const f32x4*)&b1[bo];
                f32x4 gg = *(const f32x4*)&g1[mt * 16 + q * 4];
                f32x4 be = *(const f32x4*)&be1[mt * 16 + q * 4];
                float y0 = gelu_fast((acc[mt][0] + bb[0] - mean) * rs * gg[0] + be[0]);
                float y1 = gelu_fast((acc[mt][1] + bb[1] - mean) * rs * gg[1] + be[1]);
                float y2 = gelu_fast((acc[mt][2] + bb[2] - mean) * rs * gg[2] + be[2]);
                float y3 = gelu_fast((acc[mt][3] + bb[3] - mean) * rs * gg[3] + be[3]);
                u32x2 pk; pk[0] = pkbf(y0, y1); pk[1] = pkbf(y2, y3);
                int kq = mt * 2 + (q >> 1);
                *(u32x2*)&sh_h[w][n * 64 + ((kq ^ (n & 7)) << 3) + (q & 1) * 4] = pk;
            }
        }
        // no barrier: sh_h[w] is wave-private until the block barrier below
        {
            us8 bh0 = *(const us8*)&sh_h[w][n * 64 + ((q ^ (n & 7)) << 3)];
            us8 bh1 = *(const us8*)&sh_h[w][n * 64 + (((4 + q) ^ (n & 7)) << 3)];
            f32x4 acc[4];
            #pragma unroll
            for (int mt = 0; mt < 4; ++mt) {
                us8 a0 = *(const us8*)(wt + 2048 + (mt * 16 + n) * 64 + q * 8);
                us8 a1 = *(const us8*)(wt + 2048 + (mt * 16 + n) * 64 + 32 + q * 8);
                f32x4 z = {0.f, 0.f, 0.f, 0.f};
                acc[mt] = MFMA(a0, bh0, z);
                acc[mt] = MFMA(a1, bh1, acc[mt]);
            }
            float s1 = 0.f, s2 = 0.f;
            #pragma unroll
            for (int mt = 0; mt < 4; ++mt) {
                f32x4 bb = *(const f32x4*)&b2[mt * 16 + q * 4];
                #pragma unroll
                for (int r = 0; r < 4; ++r) {
                    float x = acc[mt][r] + bb[r];
                    s1 += x; s2 += x * x;
                }
            }
            s1 += __shfl_xor(s1, 16, 64); s1 += __shfl_xor(s1, 32, 64);
            s2 += __shfl_xor(s2, 16, 64); s2 += __shfl_xor(s2, 32, 64);
            float mean = s1 * (1.f / 64.f);
            float var  = s2 * (1.f / 64.f) - mean * mean;
            float rs = __builtin_amdgcn_rsqf(var + 1e-5f);
            #pragma unroll
            for (int mt = 0; mt < 4; ++mt) {
                int bo = mt * 16 + q * 4;
                asm volatile("" : "+v"(bo));   // force bias reload (no CSE)
                f32x4 bb = *(const f32x4*)&b2[bo];
                f32x4 gg = *(const f32x4*)&g2[mt * 16 + q * 4];
                f32x4 be = *(const f32x4*)&be2[mt * 16 + q * 4];
                float y0 = gelu_fast((acc[mt][0] + bb[0] - mean) * rs * gg[0] + be[0]);
                float y1 = gelu_fast((acc[mt][1] + bb[1] - mean) * rs * gg[1] + be[1]);
                float y2 = gelu_fast((acc[mt][2] + bb[2] - mean) * rs * gg[2] + be[2]);
                float y3 = gelu_fast((acc[mt][3] + bb[3] - mean) * rs * gg[3] + be[3]);
                u32x2 pk; pk[0] = pkbf(y0, y1); pk[1] = pkbf(y2, y3);
                int kq = mt * 2 + (q >> 1);
                // overwrite h1 slot with h2 (same-wave DS ordering; proven)
                *(u32x2*)&sh_h[w][n * 64 + ((kq ^ (n & 7)) << 3) + (q & 1) * 4] = pk;
            }
        }
    }
    __syncthreads();   // barrier 1: B/C results visible

    // ---------------- Phase D: rw = h @ W3T fused with c-contraction --------
    // wave w handles o in [w*4, w*4+4) over all 64 edges, in 2 sequential
    // o-passes of 2 ops each (halves live regs; W3T bytes unchanged).
    // Results staged in sh_out (wave-disjoint o ranges -> no race).
    {
        const uint16_t* w3t = wt + 6144;
        const int ob = w * 4;
        const int dswz1 = (n & 7) << 2;   // e&7 = n&7 (e = nt*16+n)
        const int dswz2 = (n & 3) << 3;   // e&3 = n&3
        #pragma unroll 1
        for (int oc = 0; oc < 2; ++oc) {
            f32x2 p01[2][4];   // [op][nt] (m0,m1)
            float p2v[2][4];
            #pragma unroll
            for (int op = 0; op < 2; ++op)
                #pragma unroll
                for (int nt = 0; nt < 4; ++nt) {
                    p01[op][nt] = (f32x2){0.f, 0.f}; p2v[op][nt] = 0.f;
                }

            #pragma unroll 1
            for (int mt = 0; mt < 6; ++mt) {
                us8 a[2][2];
                const uint16_t* apb = w3t +
                    (size_t)((ob + oc * 2) * 96 + mt * 16 + n) * 64 + q * 8;
                #pragma unroll
                for (int op = 0; op < 2; ++op) {
                    a[op][0] = *(const us8*)(apb + (size_t)op * 6144);
                    a[op][1] = *(const us8*)(apb + (size_t)op * 6144 + 32);
                }
                #pragma unroll
                for (int nt = 0; nt < 4; ++nt) {
                    int e = nt * 16 + n;
                    // opaque offsets: defeat CSE/hoist of the bh reads so
                    // only the current nt's 16 regs are live (not 32).
                    int off0 = n * 64 + ((q ^ (n & 7)) << 3);
                    int off1 = n * 64 + (((4 + q) ^ (n & 7)) << 3);
                    asm volatile("" : "+v"(off0), "+v"(off1));
                    us8 bh0 = *(const us8*)&sh_h[nt][off0];
                    us8 bh1 = *(const us8*)&sh_h[nt][off1];
                    u32x4 d  = *(const u32x4*)&sh_t01[e * 100 + ((mt * 16 + q * 4) ^ dswz1)];
                    us4 t2   = *(const us4*)&sh_t2[e * 104 + ((mt * 16 + q * 4) ^ dswz2)];
                    f32x4 z = {0.f, 0.f, 0.f, 0.f};
                    f32x4 acc0 = MFMA(a[0][0], bh0, z);
                    acc0 = MFMA(a[0][1], bh1, acc0);
                    f32x4 acc1 = MFMA(a[1][0], bh0, z);
                    acc1 = MFMA(a[1][1], bh1, acc1);
                    #pragma unroll
                    for (int r = 0; r < 4; ++r) {
                        f32x2 f01r = up01(d[r]);
                        float fm2r = b2f(t2[r]);
                        p01[0][nt] += f01r * acc0[r];   // v_pk_fma_f32
                        p2v[0][nt] += fm2r * acc0[r];
                        p01[1][nt] += f01r * acc1[r];
                        p2v[1][nt] += fm2r * acc1[r];
                    }
                }
            }
            // reduce over q (xor 16, 32) and stage into sh_out
            #pragma unroll
            for (int nt = 0; nt < 4; ++nt) {
                #pragma unroll
                for (int op = 0; op < 2; ++op) {
                    int o = ob + oc * 2 + op;
                    float v0 = p01[op][nt][0], v1 = p01[op][nt][1], v2 = p2v[op][nt];
                    v0 += __shfl_xor(v0, 16, 64); v0 += __shfl_xor(v0, 32, 64);
                    v1 += __shfl_xor(v1, 16, 64); v1 += __shfl_xor(v1, 32, 64);
                    v2 += __shfl_xor(v2, 16, 64); v2 += __shfl_xor(v2, 32, 64);
                    float val = (q == 0) ? v0 : ((q == 1) ? v1 : v2);
                    if (q < 3)
                        sh_out[nt * 16 + n][o * 3 + q] = val;
                }
            }
        }
    }
    __syncthreads();   // barrier 2: sh_out complete

    // ---------------- Coalesced write-out: 512 thr x 3 f32x4 ----------------
    {
        f32x4* outv = (f32x4*)(out + (size_t)e0 * 96);   // 1536 vectors
        #pragma unroll
        for (int v = 0; v < 3; ++v) {
            int idx = tid + v * 512;           // vector index 0..1535
            int row = idx / 24;                // edge within block
            int col = (idx - row * 24) * 4;    // float col, 16B-aligned
            outv[idx] = *(const f32x4*)&sh_out[row][col];
        }
    }
}

// ---- launch ----------------------------------------------------------------
extern "C" void kernel_launch(void* const* d_in, const int* in_sizes, int n_in,
                              void* d_out, int out_size, void* d_ws, size_t ws_size,
                              hipStream_t stream) {
    const float* edges = (const float*)d_in[0];
    const float* feats = (const float*)d_in[1];
    const float* basis = (const float*)d_in[2];
    const float* W1  = (const float*)d_in[3];
    const float* b1  = (const float*)d_in[4];
    const float* g1  = (const float*)d_in[5];
    const float* be1 = (const float*)d_in[6];
    const float* W2  = (const float*)d_in[7];
    const float* b2  = (const float*)d_in[8];
    const float* g2  = (const float*)d_in[9];
    const float* be2 = (const float*)d_in[10];
    const float* W3  = (const float*)d_in[11];
    uint16_t* wt = (uint16_t*)d_ws;           // 202752 uint16 = 405504 B
    float* out = (float*)d_out;

    const int E = in_sizes[0] / 32;           // 32768
    hipLaunchKernelGGL(prep_weights, dim3(216), dim3(256), 0, stream, W1, W2, W3, wt);
    hipLaunchKernelGGL(pairconv_main, dim3(E / 64), dim3(512), 0, stream,
                       edges, feats, basis, b1, g1, be1, b2, g2, be2, wt, out);
}

// Round 18
// 120.657 us; speedup vs baseline: 1.0097x; 1.0097x over previous
//
#include <hip/hip_runtime.h>
#include <cstdint>
#include <cstddef>

// ---- types ----------------------------------------------------------------
typedef __bf16 bf8 __attribute__((ext_vector_type(8)));
typedef float f32x4 __attribute__((ext_vector_type(4)));
typedef float f32x2 __attribute__((ext_vector_type(2)));
typedef float f32x4u __attribute__((ext_vector_type(4), aligned(4)));
typedef unsigned short us8 __attribute__((ext_vector_type(8)));
typedef unsigned short us4 __attribute__((ext_vector_type(4)));
typedef unsigned int u32x4 __attribute__((ext_vector_type(4)));
typedef unsigned int u32x2 __attribute__((ext_vector_type(2)));

__device__ __forceinline__ uint16_t f2b(float f) {
    uint32_t u = __builtin_bit_cast(uint32_t, f);
    u += 0x7FFFu + ((u >> 16) & 1u);          // RNE
    return (uint16_t)(u >> 16);
}
__device__ __forceinline__ float b2f(uint16_t h) {
    uint32_t u = ((uint32_t)h) << 16;
    return __builtin_bit_cast(float, u);
}
#if __has_builtin(__builtin_amdgcn_cvt_pk_bf16_f32)
__device__ __forceinline__ uint32_t pkbf(float a, float b) {
    auto r = __builtin_amdgcn_cvt_pk_bf16_f32(a, b);
    return __builtin_bit_cast(uint32_t, r);
}
#else
__device__ __forceinline__ uint32_t pkbf(float a, float b) {
    return (uint32_t)f2b(a) | ((uint32_t)f2b(b) << 16);
}
#endif
__device__ __forceinline__ f32x2 up01(uint32_t d) {
    f32x2 r;
    r[0] = __builtin_bit_cast(float, d << 16);
    r[1] = __builtin_bit_cast(float, d & 0xffff0000u);
    return r;
}
__device__ __forceinline__ float gelu_fast(float y) {
    float y3 = y * y * y;
    float z2 = 1.5957691216f * (y + 0.044715f * y3);
    float u = __expf(-z2);
    return y * __builtin_amdgcn_rcpf(1.0f + u);
}

#define MFMA(a, b, c) __builtin_amdgcn_mfma_f32_16x16x32_bf16( \
    __builtin_bit_cast(bf8, (a)), __builtin_bit_cast(bf8, (b)), (c), 0, 0, 0)

// ---- prep: cast+transpose weights into ws ---------------------------------
// ws layout (uint16_t): w1t[64][32] @0, w2t[64][64] @2048, w3t[3072][64] @6144
// w3t rows permuted k = i*3+f -> k' = f*32+i (matches phase B's per-f
// sequential production; phase D mechanics unchanged).
__global__ void prep_weights(const float* __restrict__ W1,
                             const float* __restrict__ W2,
                             const float* __restrict__ W3,
                             uint16_t* __restrict__ wt) {
    __shared__ float tile[32][33];
    int bx = blockIdx.x;
    if (bx < 192) {
        int kb = (bx & 1) * 32;
        int jb = (bx >> 1) * 32;
        int tx = threadIdx.x & 31, ty = threadIdx.x >> 5;   // 32 x 8
        #pragma unroll
        for (int l = 0; l < 4; ++l)
            tile[ty + 8 * l][tx] = W3[(size_t)(kb + ty + 8 * l) * 3072 + jb + tx];
        __syncthreads();
        #pragma unroll
        for (int l = 0; l < 4; ++l) {
            unsigned j = jb + ty + 8 * l;          // source col = o*96 + i*3 + f
            unsigned o = j / 96u, rem = j - o * 96u;
            unsigned i = rem / 3u, f = rem - i * 3u;
            unsigned jp = o * 96u + f * 32u + i;   // dest row, k' = f*32+i
            wt[6144 + (size_t)jp * 64 + kb + tx] = f2b(tile[tx][ty + 8 * l]);
        }
    } else {
        int t = (bx - 192) * 256 + threadIdx.x;   // 0..6143
        if (t < 2048) {                            // W1: [32][64]
            int i = t >> 6, j = t & 63;
            wt[j * 32 + i] = f2b(W1[t]);
        } else {                                   // W2: [64][64]
            int t2 = t - 2048;
            int k = t2 >> 6, j = t2 & 63;
            wt[2048 + j * 64 + k] = f2b(W2[t2]);
        }
    }
}

// ---- fused main kernel ----------------------------------------------------
// R18 FINAL = R16 (verified session best: bench 121.1 us, main ~41 us vs
// 55.4 at session start). R17's bank swizzle REVERTED: conflicts 901K ->
// 2.75M (bank model wrong), bench neutral. R17's counters proved the R16
// structure is spill-free and traffic-ideal: VGPR 52, WRITE = 12.3 MB =
// exactly the output (the "spill" carried in the model since R6 was
// write-amplification, fully removed by sh_out staging).
// Structure: 512 thr / 8 waves / 64 edges / grid 512; phase B (per-f
// sequential, k'=f*32+i) || phase C (MFMA MLP + acc-recompute LN) on
// disjoint wave groups; barrier; phase D (rw = h @ W3T fused with
// c-contraction, 2 o-passes) staged to sh_out; barrier; coalesced f32x4
// write-out. Latency-bound at 2 blocks/CU (grid+LDS cap; 3 blocks needs
// <=85 total regs = proven spill cliff). All structural levers measured.
__global__ __launch_bounds__(512, 4) void pairconv_main(
    const float* __restrict__ edges, const float* __restrict__ feats,
    const float* __restrict__ basis,
    const float* __restrict__ b1, const float* __restrict__ g1, const float* __restrict__ be1,
    const float* __restrict__ b2, const float* __restrict__ g2, const float* __restrict__ be2,
    const uint16_t* __restrict__ wt, float* __restrict__ out) {

    __shared__ __align__(16) uint32_t sh_t01[64 * 100];   // 25.0 KiB (m0,m1 packed)
    __shared__ __align__(16) uint16_t sh_t2[64 * 104];    // 13.0 KiB (m2)
    __shared__ __align__(16) uint16_t sh_h[4][16 * 64];   // 8 KiB (h1 then h2)
    __shared__ __align__(16) float sh_out[64][100];       // 25.0 KiB (96 used + pad)

    const int tid = threadIdx.x;
    const int e0 = blockIdx.x * 64;
    const int lane = tid & 63, w = tid >> 6;              // w in 0..7
    const int n = lane & 15, q = lane >> 4;

    if (w >= 4) {
        // ---------------- Phase B (waves 4-7; per-f sequential, low-reg) ----
        const int e = (tid - 256) >> 2, iq = tid & 3;   // 64 edges x 4 quarters
        f32x4 fv[6];
        const float* fp = feats + (size_t)(e0 + e) * 96 + iq * 24;
        #pragma unroll
        for (int l = 0; l < 6; ++l) fv[l] = *(const f32x4u*)(fp + l * 4);
        const float* bpp = basis + (size_t)(e0 + e) * 27;
        const float* fvs = (const float*)fv;   // 24 floats = 8 i x 3

        #pragma unroll 1
        for (int f = 0; f < 3; ++f) {
            float bpf[9];
            #pragma unroll
            for (int m3 = 0; m3 < 3; ++m3) {   // m_in
                bpf[m3 * 3 + 0] = bpp[m3 * 9 + f * 3 + 0];
                bpf[m3 * 3 + 1] = bpp[m3 * 9 + f * 3 + 1];
                bpf[m3 * 3 + 2] = bpp[m3 * 9 + f * 3 + 2];
            }
            uint32_t t01f[8]; uint16_t t2f[8];
            #pragma unroll
            for (int ii = 0; ii < 8; ++ii) {
                float a0 = fvs[ii * 3], a1 = fvs[ii * 3 + 1], a2 = fvs[ii * 3 + 2];
                float v0 = a0 * bpf[0] + a1 * bpf[3] + a2 * bpf[6];
                float v1 = a0 * bpf[1] + a1 * bpf[4] + a2 * bpf[7];
                float v2 = a0 * bpf[2] + a1 * bpf[5] + a2 * bpf[8];
                t01f[ii] = pkbf(v0, v1);
                t2f[ii]  = (uint16_t)pkbf(v2, v2);
            }
            const int c0 = f * 32 + iq * 8;        // k' = f*32 + i
            *(u32x4*)&sh_t01[e * 100 + c0]     = *(u32x4*)&t01f[0];
            *(u32x4*)&sh_t01[e * 100 + c0 + 4] = *(u32x4*)&t01f[4];
            *(us8*)&sh_t2[e * 104 + c0]        = *(us8*)&t2f[0];
        }
    } else {
        // ---------------- Phase C (waves 0-3; LN via acc-recompute) ---------
        const int eb = e0 + w * 16;
        f32x4 ex0 = *(const f32x4*)(edges + (size_t)(eb + n) * 32 + q * 8);
        f32x4 ex1 = *(const f32x4*)(edges + (size_t)(eb + n) * 32 + q * 8 + 4);

        us8 bx;
        {
            u32x4 bxp;
            bxp[0] = pkbf(ex0[0], ex0[1]); bxp[1] = pkbf(ex0[2], ex0[3]);
            bxp[2] = pkbf(ex1[0], ex1[1]); bxp[3] = pkbf(ex1[2], ex1[3]);
            bx = __builtin_bit_cast(us8, bxp);
        }
        {
            f32x4 acc[4];
            #pragma unroll
            for (int mt = 0; mt < 4; ++mt) {
                us8 a = *(const us8*)(wt + (mt * 16 + n) * 32 + q * 8);
                f32x4 z = {0.f, 0.f, 0.f, 0.f};
                acc[mt] = MFMA(a, bx, z);
            }
            float s1 = 0.f, s2 = 0.f;
            #pragma unroll
            for (int mt = 0; mt < 4; ++mt) {
                f32x4 bb = *(const f32x4*)&b1[mt * 16 + q * 4];
                #pragma unroll
                for (int r = 0; r < 4; ++r) {
                    float x = acc[mt][r] + bb[r];
                    s1 += x; s2 += x * x;
                }
            }
            s1 += __shfl_xor(s1, 16, 64); s1 += __shfl_xor(s1, 32, 64);
            s2 += __shfl_xor(s2, 16, 64); s2 += __shfl_xor(s2, 32, 64);
            float mean = s1 * (1.f / 64.f);
            float var  = s2 * (1.f / 64.f) - mean * mean;
            float rs = __builtin_amdgcn_rsqf(var + 1e-5f);
            #pragma unroll
            for (int mt = 0; mt < 4; ++mt) {
                int bo = mt * 16 + q * 4;
                asm volatile("" : "+v"(bo));   // force bias reload (no CSE)
                f32x4 bb = *(const f32x4*)&b1[bo];
                f32x4 gg = *(const f32x4*)&g1[mt * 16 + q * 4];
                f32x4 be = *(const f32x4*)&be1[mt * 16 + q * 4];
                float y0 = gelu_fast((acc[mt][0] + bb[0] - mean) * rs * gg[0] + be[0]);
                float y1 = gelu_fast((acc[mt][1] + bb[1] - mean) * rs * gg[1] + be[1]);
                float y2 = gelu_fast((acc[mt][2] + bb[2] - mean) * rs * gg[2] + be[2]);
                float y3 = gelu_fast((acc[mt][3] + bb[3] - mean) * rs * gg[3] + be[3]);
                u32x2 pk; pk[0] = pkbf(y0, y1); pk[1] = pkbf(y2, y3);
                int kq = mt * 2 + (q >> 1);
                *(u32x2*)&sh_h[w][n * 64 + ((kq ^ (n & 7)) << 3) + (q & 1) * 4] = pk;
            }
        }
        // no barrier: sh_h[w] is wave-private until the block barrier below
        {
            us8 bh0 = *(const us8*)&sh_h[w][n * 64 + ((q ^ (n & 7)) << 3)];
            us8 bh1 = *(const us8*)&sh_h[w][n * 64 + (((4 + q) ^ (n & 7)) << 3)];
            f32x4 acc[4];
            #pragma unroll
            for (int mt = 0; mt < 4; ++mt) {
                us8 a0 = *(const us8*)(wt + 2048 + (mt * 16 + n) * 64 + q * 8);
                us8 a1 = *(const us8*)(wt + 2048 + (mt * 16 + n) * 64 + 32 + q * 8);
                f32x4 z = {0.f, 0.f, 0.f, 0.f};
                acc[mt] = MFMA(a0, bh0, z);
                acc[mt] = MFMA(a1, bh1, acc[mt]);
            }
            float s1 = 0.f, s2 = 0.f;
            #pragma unroll
            for (int mt = 0; mt < 4; ++mt) {
                f32x4 bb = *(const f32x4*)&b2[mt * 16 + q * 4];
                #pragma unroll
                for (int r = 0; r < 4; ++r) {
                    float x = acc[mt][r] + bb[r];
                    s1 += x; s2 += x * x;
                }
            }
            s1 += __shfl_xor(s1, 16, 64); s1 += __shfl_xor(s1, 32, 64);
            s2 += __shfl_xor(s2, 16, 64); s2 += __shfl_xor(s2, 32, 64);
            float mean = s1 * (1.f / 64.f);
            float var  = s2 * (1.f / 64.f) - mean * mean;
            float rs = __builtin_amdgcn_rsqf(var + 1e-5f);
            #pragma unroll
            for (int mt = 0; mt < 4; ++mt) {
                int bo = mt * 16 + q * 4;
                asm volatile("" : "+v"(bo));   // force bias reload (no CSE)
                f32x4 bb = *(const f32x4*)&b2[bo];
                f32x4 gg = *(const f32x4*)&g2[mt * 16 + q * 4];
                f32x4 be = *(const f32x4*)&be2[mt * 16 + q * 4];
                float y0 = gelu_fast((acc[mt][0] + bb[0] - mean) * rs * gg[0] + be[0]);
                float y1 = gelu_fast((acc[mt][1] + bb[1] - mean) * rs * gg[1] + be[1]);
                float y2 = gelu_fast((acc[mt][2] + bb[2] - mean) * rs * gg[2] + be[2]);
                float y3 = gelu_fast((acc[mt][3] + bb[3] - mean) * rs * gg[3] + be[3]);
                u32x2 pk; pk[0] = pkbf(y0, y1); pk[1] = pkbf(y2, y3);
                int kq = mt * 2 + (q >> 1);
                // overwrite h1 slot with h2 (same-wave DS ordering; proven)
                *(u32x2*)&sh_h[w][n * 64 + ((kq ^ (n & 7)) << 3) + (q & 1) * 4] = pk;
            }
        }
    }
    __syncthreads();   // barrier 1: B/C results visible

    // ---------------- Phase D: rw = h @ W3T fused with c-contraction --------
    // wave w handles o in [w*4, w*4+4) over all 64 edges, in 2 sequential
    // o-passes of 2 ops each (halves live regs; W3T bytes unchanged).
    // Results staged in sh_out (wave-disjoint o ranges -> no race).
    {
        const uint16_t* w3t = wt + 6144;
        const int ob = w * 4;
        #pragma unroll 1
        for (int oc = 0; oc < 2; ++oc) {
            f32x2 p01[2][4];   // [op][nt] (m0,m1)
            float p2v[2][4];
            #pragma unroll
            for (int op = 0; op < 2; ++op)
                #pragma unroll
                for (int nt = 0; nt < 4; ++nt) {
                    p01[op][nt] = (f32x2){0.f, 0.f}; p2v[op][nt] = 0.f;
                }

            #pragma unroll 1
            for (int mt = 0; mt < 6; ++mt) {
                us8 a[2][2];
                const uint16_t* apb = w3t +
                    (size_t)((ob + oc * 2) * 96 + mt * 16 + n) * 64 + q * 8;
                #pragma unroll
                for (int op = 0; op < 2; ++op) {
                    a[op][0] = *(const us8*)(apb + (size_t)op * 6144);
                    a[op][1] = *(const us8*)(apb + (size_t)op * 6144 + 32);
                }
                #pragma unroll
                for (int nt = 0; nt < 4; ++nt) {
                    int e = nt * 16 + n;
                    // opaque offsets: defeat CSE/hoist of the bh reads so
                    // only the current nt's 16 regs are live (not 32).
                    int off0 = n * 64 + ((q ^ (n & 7)) << 3);
                    int off1 = n * 64 + (((4 + q) ^ (n & 7)) << 3);
                    asm volatile("" : "+v"(off0), "+v"(off1));
                    us8 bh0 = *(const us8*)&sh_h[nt][off0];
                    us8 bh1 = *(const us8*)&sh_h[nt][off1];
                    u32x4 d  = *(const u32x4*)&sh_t01[e * 100 + mt * 16 + q * 4];
                    us4 t2   = *(const us4*)&sh_t2[e * 104 + mt * 16 + q * 4];
                    f32x4 z = {0.f, 0.f, 0.f, 0.f};
                    f32x4 acc0 = MFMA(a[0][0], bh0, z);
                    acc0 = MFMA(a[0][1], bh1, acc0);
                    f32x4 acc1 = MFMA(a[1][0], bh0, z);
                    acc1 = MFMA(a[1][1], bh1, acc1);
                    #pragma unroll
                    for (int r = 0; r < 4; ++r) {
                        f32x2 f01r = up01(d[r]);
                        float fm2r = b2f(t2[r]);
                        p01[0][nt] += f01r * acc0[r];   // v_pk_fma_f32
                        p2v[0][nt] += fm2r * acc0[r];
                        p01[1][nt] += f01r * acc1[r];
                        p2v[1][nt] += fm2r * acc1[r];
                    }
                }
            }
            // reduce over q (xor 16, 32) and stage into sh_out
            #pragma unroll
            for (int nt = 0; nt < 4; ++nt) {
                #pragma unroll
                for (int op = 0; op < 2; ++op) {
                    int o = ob + oc * 2 + op;
                    float v0 = p01[op][nt][0], v1 = p01[op][nt][1], v2 = p2v[op][nt];
                    v0 += __shfl_xor(v0, 16, 64); v0 += __shfl_xor(v0, 32, 64);
                    v1 += __shfl_xor(v1, 16, 64); v1 += __shfl_xor(v1, 32, 64);
                    v2 += __shfl_xor(v2, 16, 64); v2 += __shfl_xor(v2, 32, 64);
                    float val = (q == 0) ? v0 : ((q == 1) ? v1 : v2);
                    if (q < 3)
                        sh_out[nt * 16 + n][o * 3 + q] = val;
                }
            }
        }
    }
    __syncthreads();   // barrier 2: sh_out complete

    // ---------------- Coalesced write-out: 512 thr x 3 f32x4 ----------------
    {
        f32x4* outv = (f32x4*)(out + (size_t)e0 * 96);   // 1536 vectors
        #pragma unroll
        for (int v = 0; v < 3; ++v) {
            int idx = tid + v * 512;           // vector index 0..1535
            int row = idx / 24;                // edge within block
            int col = (idx - row * 24) * 4;    // float col, 16B-aligned
            outv[idx] = *(const f32x4*)&sh_out[row][col];
        }
    }
}

// ---- launch ----------------------------------------------------------------
extern "C" void kernel_launch(void* const* d_in, const int* in_sizes, int n_in,
                              void* d_out, int out_size, void* d_ws, size_t ws_size,
                              hipStream_t stream) {
    const float* edges = (const float*)d_in[0];
    const float* feats = (const float*)d_in[1];
    const float* basis = (const float*)d_in[2];
    const float* W1  = (const float*)d_in[3];
    const float* b1  = (const float*)d_in[4];
    const float* g1  = (const float*)d_in[5];
    const float* be1 = (const float*)d_in[6];
    const float* W2  = (const float*)d_in[7];
    const float* b2  = (const float*)d_in[8];
    const float* g2  = (const float*)d_in[9];
    const float* be2 = (const float*)d_in[10];
    const float* W3  = (const float*)d_in[11];
    uint16_t* wt = (uint16_t*)d_ws;           // 202752 uint16 = 405504 B
    float* out = (float*)d_out;

    const int E = in_sizes[0] / 32;           // 32768
    hipLaunchKernelGGL(prep_weights, dim3(216), dim3(256), 0, stream, W1, W2, W3, wt);
    hipLaunchKernelGGL(pairconv_main, dim3(E / 64), dim3(512), 0, stream,
                       edges, feats, basis, b1, g1, be1, b2, g2, be2, wt, out);
}